// Round 7
// baseline (123.161 us; speedup 1.0000x reference)
//
#include <hip/hip_runtime.h>
#include <hip/hip_bf16.h>
#include <math.h>

#define S_LEN 1024
#define DM    256
#define DU    32
#define TEMPF 5.0f

typedef float f32x4  __attribute__((ext_vector_type(4)));
typedef short bf16x8 __attribute__((ext_vector_type(8)));   // 8 bf16 (4 VGPRs)

__device__ __forceinline__ unsigned short f32_to_bf16_rne(float x) {
    unsigned int b = __float_as_uint(x);
    b += 0x7FFFu + ((b >> 16) & 1u);
    return (unsigned short)(b >> 16);
}

// ---------------------------------------------------------------------------
// Kernel A: fused QKV projection (unchanged from round 6, proven at 118.6).
// ---------------------------------------------------------------------------
__global__ __launch_bounds__(256) void qkv_proj_kernel(
    const float* __restrict__ x,
    const float* __restrict__ Wq, const float* __restrict__ bq,
    const float* __restrict__ Wk, const float* __restrict__ bk,
    const float* __restrict__ Wv, const float* __restrict__ bv,
    float* __restrict__ qo, float* __restrict__ ko, float* __restrict__ vo)
{
    const int mat = blockIdx.z;
    const float* __restrict__ W    = (mat == 0) ? Wq : ((mat == 1) ? Wk : Wv);
    const float* __restrict__ bias = (mat == 0) ? bq : ((mat == 1) ? bk : bv);
    float* __restrict__ dst        = (mat == 0) ? qo : ((mat == 1) ? ko : vo);

    const int n0 = blockIdx.x * 64;
    const int m0 = blockIdx.y * 32;
    const int t  = threadIdx.x;
    const int tx = t & 15;
    const int ty = t >> 4;

    __shared__ float xs[2][32][36];   // transposed [k][row]
    __shared__ float wsh[2][32][68];  // [k][n]

    float acc[2][4] = {};

    const int xrow = t & 31;
    const int xkc  = (t >> 5) * 4;
    const int wrow = t >> 4;
    const int wcol = (t & 15) * 4;

    float4 xa = *(const float4*)&x[(m0 + xrow) * DM + xkc];
    float4 wa = *(const float4*)&W[wrow * DM + n0 + wcol];
    float4 wb = *(const float4*)&W[(wrow + 16) * DM + n0 + wcol];
    xs[0][xkc + 0][xrow] = xa.x; xs[0][xkc + 1][xrow] = xa.y;
    xs[0][xkc + 2][xrow] = xa.z; xs[0][xkc + 3][xrow] = xa.w;
    *(float4*)&wsh[0][wrow][wcol]      = wa;
    *(float4*)&wsh[0][wrow + 16][wcol] = wb;
    __syncthreads();

    int cur = 0;
    for (int k0 = 32; k0 < DM; k0 += 32) {
        xa = *(const float4*)&x[(m0 + xrow) * DM + k0 + xkc];
        wa = *(const float4*)&W[(k0 + wrow) * DM + n0 + wcol];
        wb = *(const float4*)&W[(k0 + wrow + 16) * DM + n0 + wcol];
        #pragma unroll
        for (int kk = 0; kk < 32; kk++) {
            float2 a2 = *(const float2*)&xs[cur][kk][ty * 2];
            float4 b4 = *(const float4*)&wsh[cur][kk][tx * 4];
            acc[0][0] += a2.x * b4.x; acc[0][1] += a2.x * b4.y;
            acc[0][2] += a2.x * b4.z; acc[0][3] += a2.x * b4.w;
            acc[1][0] += a2.y * b4.x; acc[1][1] += a2.y * b4.y;
            acc[1][2] += a2.y * b4.z; acc[1][3] += a2.y * b4.w;
        }
        const int nxt = cur ^ 1;
        xs[nxt][xkc + 0][xrow] = xa.x; xs[nxt][xkc + 1][xrow] = xa.y;
        xs[nxt][xkc + 2][xrow] = xa.z; xs[nxt][xkc + 3][xrow] = xa.w;
        *(float4*)&wsh[nxt][wrow][wcol]      = wa;
        *(float4*)&wsh[nxt][wrow + 16][wcol] = wb;
        __syncthreads();
        cur = nxt;
    }
    #pragma unroll
    for (int kk = 0; kk < 32; kk++) {
        float2 a2 = *(const float2*)&xs[cur][kk][ty * 2];
        float4 b4 = *(const float4*)&wsh[cur][kk][tx * 4];
        acc[0][0] += a2.x * b4.x; acc[0][1] += a2.x * b4.y;
        acc[0][2] += a2.x * b4.z; acc[0][3] += a2.x * b4.w;
        acc[1][0] += a2.y * b4.x; acc[1][1] += a2.y * b4.y;
        acc[1][2] += a2.y * b4.z; acc[1][3] += a2.y * b4.w;
    }

    #pragma unroll
    for (int j = 0; j < 4; j++) {
        const int cidx = n0 + tx * 4 + j;
        const float bb = bias[cidx];
        const int hh = cidx >> 5;
        const int dd = cidx & 31;
        #pragma unroll
        for (int i = 0; i < 2; i++) {
            const int row = m0 + ty * 2 + i;
            float val = acc[i][j] + bb;
            if (mat < 2) val = 1.0f / (1.0f + __expf(-val));
            dst[hh * (S_LEN * DU) + row * DU + dd] = val;
        }
    }
}

// ---------------------------------------------------------------------------
// Kernel B: fuzzy-implication attention, causal, ONE j-tile per block.
// Grid = 8 heads * sum_{it4=0..15}(it4+1) = 1088 uniform blocks, 256 thr.
// bid -> (h, it4, jt) via triangular decode. No online max (z in [0,5]).
// Phase 1 (VALU): scores + exp; p written to LDS as bf16 row-major.
// Phase 2 (MFMA): o[64x32] += P[64x64]_bf16 @ V[64x32]_bf16 via
// mfma_f32_16x16x32_bf16 (A row-major contiguous b128, B from transposed Vt).
// Partials (o, l) per task; combine_kernel sums variable it4+1 splits.
// ---------------------------------------------------------------------------
__global__ __launch_bounds__(256, 2) void attn_kernel(
    const float* __restrict__ q, const float* __restrict__ k,
    const float* __restrict__ v,
    float* __restrict__ part_o, float* __restrict__ part_l)
{
    const int bid = blockIdx.x;
    const int h   = bid / 136;
    const int rem = bid - h * 136;
    int it4 = (int)((sqrtf(8.0f * (float)rem + 1.0f) - 1.0f) * 0.5f);
    while ((it4 + 1) * (it4 + 2) / 2 <= rem) it4++;
    while (it4 * (it4 + 1) / 2 > rem) it4--;
    const int jt = rem - it4 * (it4 + 1) / 2;
    const int i0 = it4 * 64;

    const int t = threadIdx.x;
    const int r = t >> 4;      // 0..15
    const int c = t & 15;      // 0..15
    const int w = t >> 6;      // wave 0..3

    __shared__ __align__(16) float          Ks[64][36];   // fp32 scores input
    __shared__ __align__(16) unsigned short Vt[32][88];   // [d][j] bf16 (B-op)
    __shared__ __align__(16) unsigned short Ps[64][88];   // [row][j] bf16 (A-op)

    // Q rows (r+16kq) into registers; fp32 for score accuracy
    float qreg[4][32];
    #pragma unroll
    for (int kq = 0; kq < 4; kq++) {
        const float* qrow = q + h * (S_LEN * DU) + (i0 + r + 16 * kq) * DU;
        #pragma unroll
        for (int d4 = 0; d4 < 8; d4++) {
            float4 qv = *(const float4*)&qrow[d4 * 4];
            qreg[kq][d4*4+0] = qv.x; qreg[kq][d4*4+1] = qv.y;
            qreg[kq][d4*4+2] = qv.z; qreg[kq][d4*4+3] = qv.w;
        }
    }

    // ---- stage K (fp32) and V (bf16, transposed) ----
    {
        const int jr = t >> 2;            // 0..63
        const int d0 = (t & 3) * 8;       // 0,8,16,24
        const float* kp = k + h * (S_LEN * DU) + (jt * 64 + jr) * DU + d0;
        const float* vp = v + h * (S_LEN * DU) + (jt * 64 + jr) * DU + d0;
        float4 ka = *(const float4*)kp, kb = *(const float4*)(kp + 4);
        float4 va = *(const float4*)vp, vb = *(const float4*)(vp + 4);
        *(float4*)&Ks[jr][d0]     = ka;
        *(float4*)&Ks[jr][d0 + 4] = kb;
        float vv[8] = {va.x, va.y, va.z, va.w, vb.x, vb.y, vb.z, vb.w};
        #pragma unroll
        for (int i = 0; i < 8; i++)
            Vt[d0 + i][jr] = f32_to_bf16_rne(vv[i]);
    }
    __syncthreads();

    // ---- phase 1: scores (VALU) -> p -> Ps (bf16) + l partials ----
    float lpart[4] = {0.0f, 0.0f, 0.0f, 0.0f};
    #pragma unroll
    for (int q4 = 0; q4 < 4; q4++) {
        const int jj  = c + q4 * 16;
        const int jgl = jt * 64 + jj;
        float sacc[4] = {0.0f, 0.0f, 0.0f, 0.0f};
        #pragma unroll
        for (int d = 0; d < 32; d += 4) {
            float4 k4 = *(const float4*)&Ks[jj][d];
            #pragma unroll
            for (int kq = 0; kq < 4; kq++) {
                sacc[kq] += fmaxf(qreg[kq][d+0] - k4.x, 0.0f)
                          + fmaxf(qreg[kq][d+1] - k4.y, 0.0f)
                          + fmaxf(qreg[kq][d+2] - k4.z, 0.0f)
                          + fmaxf(qreg[kq][d+3] - k4.w, 0.0f);
            }
        }
        #pragma unroll
        for (int kq = 0; kq < 4; kq++) {
            const int ig = i0 + r + 16 * kq;
            const float p = (jgl <= ig)
                ? __expf(TEMPF - (TEMPF / 32.0f) * sacc[kq]) : 0.0f;
            lpart[kq] += p;
            Ps[r + 16 * kq][jj] = f32_to_bf16_rne(p);
        }
    }
    #pragma unroll
    for (int off = 8; off; off >>= 1)
        #pragma unroll
        for (int kq = 0; kq < 4; kq++)
            lpart[kq] += __shfl_xor(lpart[kq], off, 16);
    __syncthreads();   // Ps (cross-wave) visible for MFMA phase

    // ---- phase 2: PV via MFMA. Wave w owns rows [16w, 16w+16). ----
    const int lane = t & 63;
    const int m    = lane & 15;
    const int quad = lane >> 4;
    f32x4 acc0 = {0.0f, 0.0f, 0.0f, 0.0f};
    f32x4 acc1 = {0.0f, 0.0f, 0.0f, 0.0f};
    #pragma unroll
    for (int kc = 0; kc < 2; kc++) {
        bf16x8 a  = *(const bf16x8*)&Ps[16 * w + m][kc * 32 + quad * 8];
        bf16x8 b0 = *(const bf16x8*)&Vt[m]     [kc * 32 + quad * 8];
        bf16x8 b1 = *(const bf16x8*)&Vt[m + 16][kc * 32 + quad * 8];
        acc0 = __builtin_amdgcn_mfma_f32_16x16x32_bf16(a, b0, acc0, 0, 0, 0);
        acc1 = __builtin_amdgcn_mfma_f32_16x16x32_bf16(a, b1, acc1, 0, 0, 0);
    }

    // ---- write partials: D layout row=16w+quad*4+reg, col=lane&15 ----
    float* po = part_o + (size_t)bid * 2048;
    #pragma unroll
    for (int reg = 0; reg < 4; reg++) {
        const int row = 16 * w + quad * 4 + reg;
        po[row * 32 + m]      = acc0[reg];
        po[row * 32 + m + 16] = acc1[reg];
    }
    if (c == 0) {
        #pragma unroll
        for (int kq = 0; kq < 4; kq++)
            part_l[bid * 64 + r + 16 * kq] = lpart[kq];
    }
}

// ---------------------------------------------------------------------------
// Kernel B2: combine it4+1 partials -> attn [s][256].
// Grid 128 = 8h x 16 it4, 256 threads; thread handles 2 float4 slots.
// ---------------------------------------------------------------------------
__global__ __launch_bounds__(256) void combine_kernel(
    const float* __restrict__ part_o, const float* __restrict__ part_l,
    float* __restrict__ attn)
{
    const int h   = blockIdx.x & 7;
    const int it4 = blockIdx.x >> 3;
    const int t0  = h * 136 + it4 * (it4 + 1) / 2;
    const int cnt = it4 + 1;
    const int t   = threadIdx.x;

    #pragma unroll
    for (int ss = 0; ss < 2; ss++) {
        const int slot = t * 2 + ss;          // 0..511
        const int row  = slot >> 3;
        const int d4   = (slot & 7) * 4;
        float4 o = make_float4(0.f, 0.f, 0.f, 0.f);
        float  l = 0.0f;
        for (int j = 0; j < cnt; j++) {
            float4 p = *(const float4*)&part_o[(size_t)(t0 + j) * 2048 + row * 32 + d4];
            o.x += p.x; o.y += p.y; o.z += p.z; o.w += p.w;
            l += part_l[(t0 + j) * 64 + row];
        }
        const float inv = 1.0f / l;
        float4 res = make_float4(o.x * inv, o.y * inv, o.z * inv, o.w * inv);
        *(float4*)&attn[(it4 * 64 + row) * DM + h * 32 + d4] = res;
    }
}

// ---------------------------------------------------------------------------
// Kernel C: output projection (unchanged from round 6, proven at 118.6).
// ---------------------------------------------------------------------------
__global__ __launch_bounds__(256) void out_proj_kernel(
    const float* __restrict__ a, const float* __restrict__ W,
    const float* __restrict__ bias, float* __restrict__ dst)
{
    const int n0 = blockIdx.x * 32;
    const int m0 = blockIdx.y * 32;
    const int t  = threadIdx.x;
    const int tx = t & 15;
    const int ty = t >> 4;

    __shared__ float xs[2][32][36];
    __shared__ float wsh[2][32][36];

    float acc[2][2] = {};

    const int arow = t & 31;
    const int akc  = (t >> 5) * 4;
    const int wr   = t >> 3;
    const int wc   = (t & 7) * 4;

    float4 xa = *(const float4*)&a[(m0 + arow) * DM + akc];
    float4 wa = *(const float4*)&W[wr * DM + n0 + wc];
    xs[0][akc + 0][arow] = xa.x; xs[0][akc + 1][arow] = xa.y;
    xs[0][akc + 2][arow] = xa.z; xs[0][akc + 3][arow] = xa.w;
    *(float4*)&wsh[0][wr][wc] = wa;
    __syncthreads();

    int cur = 0;
    for (int k0 = 32; k0 < DM; k0 += 32) {
        xa = *(const float4*)&a[(m0 + arow) * DM + k0 + akc];
        wa = *(const float4*)&W[(k0 + wr) * DM + n0 + wc];
        #pragma unroll
        for (int kk = 0; kk < 32; kk++) {
            float2 a2 = *(const float2*)&xs[cur][kk][ty * 2];
            float2 b2 = *(const float2*)&wsh[cur][kk][tx * 2];
            acc[0][0] += a2.x * b2.x; acc[0][1] += a2.x * b2.y;
            acc[1][0] += a2.y * b2.x; acc[1][1] += a2.y * b2.y;
        }
        const int nxt = cur ^ 1;
        xs[nxt][akc + 0][arow] = xa.x; xs[nxt][akc + 1][arow] = xa.y;
        xs[nxt][akc + 2][arow] = xa.z; xs[nxt][akc + 3][arow] = xa.w;
        *(float4*)&wsh[nxt][wr][wc] = wa;
        __syncthreads();
        cur = nxt;
    }
    #pragma unroll
    for (int kk = 0; kk < 32; kk++) {
        float2 a2 = *(const float2*)&xs[cur][kk][ty * 2];
        float2 b2 = *(const float2*)&wsh[cur][kk][tx * 2];
        acc[0][0] += a2.x * b2.x; acc[0][1] += a2.x * b2.y;
        acc[1][0] += a2.y * b2.x; acc[1][1] += a2.y * b2.y;
    }

    #pragma unroll
    for (int j = 0; j < 2; j++) {
        const int cidx = n0 + tx * 2 + j;
        const float bb = bias[cidx];
        #pragma unroll
        for (int i = 0; i < 2; i++) {
            const int row = m0 + ty * 2 + i;
            dst[row * DM + cidx] = acc[i][j] + bb;
        }
    }
}

// ---------------------------------------------------------------------------
extern "C" void kernel_launch(void* const* d_in, const int* in_sizes, int n_in,
                              void* d_out, int out_size, void* d_ws, size_t ws_size,
                              hipStream_t stream)
{
    const float* x  = (const float*)d_in[0];
    const float* Wq = (const float*)d_in[1];
    const float* bq = (const float*)d_in[2];
    const float* Wk = (const float*)d_in[3];
    const float* bk = (const float*)d_in[4];
    const float* Wv = (const float*)d_in[5];
    const float* bv = (const float*)d_in[6];
    const float* Wo = (const float*)d_in[7];
    const float* bo = (const float*)d_in[8];
    float* out = (float*)d_out;

    float* ws      = (float*)d_ws;
    float* q       = ws;                      // [8][1024][32] = 262144
    float* k       = q + 262144;
    float* v       = k + 262144;
    float* attn    = v + 262144;              // [1024][256]  = 262144
    float* part_o  = attn + 262144;           // 1088 * 2048  = 2228224
    float* part_l  = part_o + 2228224;        // 1088 * 64    = 69632
    // total ~13.4 MB

    qkv_proj_kernel<<<dim3(4, 32, 3), 256, 0, stream>>>(x, Wq, bq, Wk, bk, Wv, bv, q, k, v);
    attn_kernel<<<dim3(1088), 256, 0, stream>>>(q, k, v, part_o, part_l);
    combine_kernel<<<dim3(128), 256, 0, stream>>>(part_o, part_l, attn);
    out_proj_kernel<<<dim3(8, 32), 256, 0, stream>>>(attn, Wo, bo, out);
}

// Round 8
// 111.772 us; speedup vs baseline: 1.1019x; 1.1019x over previous
//
#include <hip/hip_runtime.h>
#include <hip/hip_bf16.h>
#include <math.h>

#define S_LEN 1024
#define DM    256
#define DU    32
#define TEMPF 5.0f
#define NS    4          // attention j-splits

typedef float f32x4  __attribute__((ext_vector_type(4)));
typedef short bf16x8 __attribute__((ext_vector_type(8)));   // 8 bf16 (4 VGPRs)

__device__ __forceinline__ unsigned short f32_to_bf16_rne(float x) {
    unsigned int b = __float_as_uint(x);
    b += 0x7FFFu + ((b >> 16) & 1u);
    return (unsigned short)(b >> 16);
}

// ---------------------------------------------------------------------------
// Kernel A: fused QKV projection (unchanged from round 6, proven at 118.6).
// ---------------------------------------------------------------------------
__global__ __launch_bounds__(256) void qkv_proj_kernel(
    const float* __restrict__ x,
    const float* __restrict__ Wq, const float* __restrict__ bq,
    const float* __restrict__ Wk, const float* __restrict__ bk,
    const float* __restrict__ Wv, const float* __restrict__ bv,
    float* __restrict__ qo, float* __restrict__ ko, float* __restrict__ vo)
{
    const int mat = blockIdx.z;
    const float* __restrict__ W    = (mat == 0) ? Wq : ((mat == 1) ? Wk : Wv);
    const float* __restrict__ bias = (mat == 0) ? bq : ((mat == 1) ? bk : bv);
    float* __restrict__ dst        = (mat == 0) ? qo : ((mat == 1) ? ko : vo);

    const int n0 = blockIdx.x * 64;
    const int m0 = blockIdx.y * 32;
    const int t  = threadIdx.x;
    const int tx = t & 15;
    const int ty = t >> 4;

    __shared__ float xs[2][32][36];   // transposed [k][row]
    __shared__ float wsh[2][32][68];  // [k][n]

    float acc[2][4] = {};

    const int xrow = t & 31;
    const int xkc  = (t >> 5) * 4;
    const int wrow = t >> 4;
    const int wcol = (t & 15) * 4;

    float4 xa = *(const float4*)&x[(m0 + xrow) * DM + xkc];
    float4 wa = *(const float4*)&W[wrow * DM + n0 + wcol];
    float4 wb = *(const float4*)&W[(wrow + 16) * DM + n0 + wcol];
    xs[0][xkc + 0][xrow] = xa.x; xs[0][xkc + 1][xrow] = xa.y;
    xs[0][xkc + 2][xrow] = xa.z; xs[0][xkc + 3][xrow] = xa.w;
    *(float4*)&wsh[0][wrow][wcol]      = wa;
    *(float4*)&wsh[0][wrow + 16][wcol] = wb;
    __syncthreads();

    int cur = 0;
    for (int k0 = 32; k0 < DM; k0 += 32) {
        xa = *(const float4*)&x[(m0 + xrow) * DM + k0 + xkc];
        wa = *(const float4*)&W[(k0 + wrow) * DM + n0 + wcol];
        wb = *(const float4*)&W[(k0 + wrow + 16) * DM + n0 + wcol];
        #pragma unroll
        for (int kk = 0; kk < 32; kk++) {
            float2 a2 = *(const float2*)&xs[cur][kk][ty * 2];
            float4 b4 = *(const float4*)&wsh[cur][kk][tx * 4];
            acc[0][0] += a2.x * b4.x; acc[0][1] += a2.x * b4.y;
            acc[0][2] += a2.x * b4.z; acc[0][3] += a2.x * b4.w;
            acc[1][0] += a2.y * b4.x; acc[1][1] += a2.y * b4.y;
            acc[1][2] += a2.y * b4.z; acc[1][3] += a2.y * b4.w;
        }
        const int nxt = cur ^ 1;
        xs[nxt][xkc + 0][xrow] = xa.x; xs[nxt][xkc + 1][xrow] = xa.y;
        xs[nxt][xkc + 2][xrow] = xa.z; xs[nxt][xkc + 3][xrow] = xa.w;
        *(float4*)&wsh[nxt][wrow][wcol]      = wa;
        *(float4*)&wsh[nxt][wrow + 16][wcol] = wb;
        __syncthreads();
        cur = nxt;
    }
    #pragma unroll
    for (int kk = 0; kk < 32; kk++) {
        float2 a2 = *(const float2*)&xs[cur][kk][ty * 2];
        float4 b4 = *(const float4*)&wsh[cur][kk][tx * 4];
        acc[0][0] += a2.x * b4.x; acc[0][1] += a2.x * b4.y;
        acc[0][2] += a2.x * b4.z; acc[0][3] += a2.x * b4.w;
        acc[1][0] += a2.y * b4.x; acc[1][1] += a2.y * b4.y;
        acc[1][2] += a2.y * b4.z; acc[1][3] += a2.y * b4.w;
    }

    #pragma unroll
    for (int j = 0; j < 4; j++) {
        const int cidx = n0 + tx * 4 + j;
        const float bb = bias[cidx];
        const int hh = cidx >> 5;
        const int dd = cidx & 31;
        #pragma unroll
        for (int i = 0; i < 2; i++) {
            const int row = m0 + ty * 2 + i;
            float val = acc[i][j] + bb;
            if (mat < 2) val = 1.0f / (1.0f + __expf(-val));
            dst[hh * (S_LEN * DU) + row * DU + dd] = val;
        }
    }
}

// ---------------------------------------------------------------------------
// Kernel B: fuzzy-implication attention, causal, j-split, MFMA PV.
// R6 block structure (512 blocks = 8h x 16 it4 x NS splits, LPT, Q loaded
// once, register prefetch) + R7's verified bf16 MFMA PV phase.
// No online max (z in [0,5]); MFMA accumulators persist across j-tiles.
// Phase 1 (VALU, fp32): scores + exp -> Ps bf16.  Phase 2: 4x
// mfma_f32_16x16x32_bf16 per wave-tile (A=Ps rows 16w.., B=Vt transposed).
// ---------------------------------------------------------------------------
__global__ __launch_bounds__(256, 2) void attn_kernel(
    const float* __restrict__ q, const float* __restrict__ k,
    const float* __restrict__ v,
    float* __restrict__ part_o, float* __restrict__ part_l)
{
    const int bid = blockIdx.x;
    const int it4 = 15 - (bid >> 5);      // LPT: heavy first
    const int sub = bid & 31;
    const int h   = sub & 7;
    const int s   = sub >> 3;             // split 0..NS-1
    const int t   = threadIdx.x;
    const int r   = t >> 4;               // 0..15
    const int c   = t & 15;               // 0..15
    const int w   = t >> 6;               // wave 0..3
    const int i0  = it4 * 64;

    __shared__ __align__(16) float          Ks[64][36];   // fp32 score input
    __shared__ __align__(16) unsigned short Vt[32][88];   // [d][j] bf16 (B-op)
    __shared__ __align__(16) unsigned short Ps[64][88];   // [row][j] bf16 (A-op)

    // Q rows (r+16kq) into registers, once per block (fp32 for score accuracy)
    float qreg[4][32];
    #pragma unroll
    for (int kq = 0; kq < 4; kq++) {
        const float* qrow = q + h * (S_LEN * DU) + (i0 + r + 16 * kq) * DU;
        #pragma unroll
        for (int d4 = 0; d4 < 8; d4++) {
            float4 qv = *(const float4*)&qrow[d4 * 4];
            qreg[kq][d4*4+0] = qv.x; qreg[kq][d4*4+1] = qv.y;
            qreg[kq][d4*4+2] = qv.z; qreg[kq][d4*4+3] = qv.w;
        }
    }

    float lpart[4] = {0.0f, 0.0f, 0.0f, 0.0f};
    f32x4 acc0 = {0.0f, 0.0f, 0.0f, 0.0f};
    f32x4 acc1 = {0.0f, 0.0f, 0.0f, 0.0f};

    const int jr = t >> 2;            // 0..63 staging row
    const int d0 = (t & 3) * 8;       // staging d-offset
    const float* kbase = k + h * (S_LEN * DU);
    const float* vbase = v + h * (S_LEN * DU);

    const int lane = t & 63;
    const int m    = lane & 15;
    const int quad = lane >> 4;

    const int njt = it4 + 1;
    float4 ka, kb, va, vb;
    if (s < njt) {
        const float* kp = kbase + (s * 64 + jr) * DU + d0;
        const float* vp = vbase + (s * 64 + jr) * DU + d0;
        ka = *(const float4*)kp; kb = *(const float4*)(kp + 4);
        va = *(const float4*)vp; vb = *(const float4*)(vp + 4);
    }

    for (int jt = s; jt < njt; jt += NS) {
        __syncthreads();   // prev tile fully consumed (Ks phase-1, Vt/Ps phase-2)
        *(float4*)&Ks[jr][d0]     = ka;
        *(float4*)&Ks[jr][d0 + 4] = kb;
        {
            float vv[8] = {va.x, va.y, va.z, va.w, vb.x, vb.y, vb.z, vb.w};
            #pragma unroll
            for (int i = 0; i < 8; i++)
                Vt[d0 + i][jr] = f32_to_bf16_rne(vv[i]);
        }
        __syncthreads();
        if (jt + NS < njt) {          // prefetch next tile (hidden by compute)
            const float* kp = kbase + ((jt + NS) * 64 + jr) * DU + d0;
            const float* vp = vbase + ((jt + NS) * 64 + jr) * DU + d0;
            ka = *(const float4*)kp; kb = *(const float4*)(kp + 4);
            va = *(const float4*)vp; vb = *(const float4*)(vp + 4);
        }

        // ---- phase 1: scores (fp32 VALU) -> p -> Ps bf16 + l partials ----
        #pragma unroll
        for (int q4 = 0; q4 < 4; q4++) {
            const int jj  = c + q4 * 16;
            const int jgl = jt * 64 + jj;
            float sacc[4] = {0.0f, 0.0f, 0.0f, 0.0f};
            #pragma unroll
            for (int d = 0; d < 32; d += 4) {
                float4 k4 = *(const float4*)&Ks[jj][d];
                #pragma unroll
                for (int kq = 0; kq < 4; kq++) {
                    sacc[kq] += fmaxf(qreg[kq][d+0] - k4.x, 0.0f)
                              + fmaxf(qreg[kq][d+1] - k4.y, 0.0f)
                              + fmaxf(qreg[kq][d+2] - k4.z, 0.0f)
                              + fmaxf(qreg[kq][d+3] - k4.w, 0.0f);
                }
            }
            #pragma unroll
            for (int kq = 0; kq < 4; kq++) {
                const int ig = i0 + r + 16 * kq;
                const float p = (jgl <= ig)
                    ? __expf(TEMPF - (TEMPF / 32.0f) * sacc[kq]) : 0.0f;
                lpart[kq] += p;
                Ps[r + 16 * kq][jj] = f32_to_bf16_rne(p);
            }
        }
        __syncthreads();   // Ps visible cross-wave for MFMA phase

        // ---- phase 2: PV via MFMA, accumulate across j-tiles ----
        #pragma unroll
        for (int kc = 0; kc < 2; kc++) {
            bf16x8 a  = *(const bf16x8*)&Ps[16 * w + m][kc * 32 + quad * 8];
            bf16x8 b0 = *(const bf16x8*)&Vt[m]     [kc * 32 + quad * 8];
            bf16x8 b1 = *(const bf16x8*)&Vt[m + 16][kc * 32 + quad * 8];
            acc0 = __builtin_amdgcn_mfma_f32_16x16x32_bf16(a, b0, acc0, 0, 0, 0);
            acc1 = __builtin_amdgcn_mfma_f32_16x16x32_bf16(a, b1, acc1, 0, 0, 0);
        }
    }

    // l: reduce each row's partials over its 16 lanes
    #pragma unroll
    for (int off = 8; off; off >>= 1)
        #pragma unroll
        for (int kq = 0; kq < 4; kq++)
            lpart[kq] += __shfl_xor(lpart[kq], off, 16);

    // write partials: D layout row = 16w + quad*4 + reg, col = m / m+16
    const int pbase = (h * 16 + it4) * NS + s;
    float* po = part_o + (size_t)pbase * 2048;
    #pragma unroll
    for (int reg = 0; reg < 4; reg++) {
        const int row = 16 * w + quad * 4 + reg;
        po[row * 32 + m]      = acc0[reg];
        po[row * 32 + m + 16] = acc1[reg];
    }
    if (c == 0) {
        #pragma unroll
        for (int kq = 0; kq < 4; kq++)
            part_l[pbase * 64 + r + 16 * kq] = lpart[kq];
    }
}

// ---------------------------------------------------------------------------
// Kernel B2: combine NS split partials (plain sums).  Grid 128, 256 thr.
// (Unchanged from round 6, proven.)
// ---------------------------------------------------------------------------
__global__ __launch_bounds__(256) void combine_kernel(
    const float* __restrict__ part_o, const float* __restrict__ part_l,
    float* __restrict__ attn)
{
    const int h    = blockIdx.x & 7;
    const int it4  = blockIdx.x >> 3;
    const int t    = threadIdx.x;
    const int r    = t >> 4;
    const int c    = t & 15;
    const int base = (h * 16 + it4) * NS;

    #pragma unroll
    for (int kq = 0; kq < 4; kq++) {
        const int row = r + 16 * kq;
        float os0 = 0.0f, os1 = 0.0f, ls = 0.0f;
        #pragma unroll
        for (int s2 = 0; s2 < NS; s2++) {
            const float* po = part_o + (size_t)(base + s2) * 2048;
            os0 += po[row * 32 + c];
            os1 += po[row * 32 + c + 16];
            ls  += part_l[(base + s2) * 64 + row];
        }
        const float inv = 1.0f / ls;
        attn[(it4 * 64 + row) * DM + h * DU + c]      = os0 * inv;
        attn[(it4 * 64 + row) * DM + h * DU + c + 16] = os1 * inv;
    }
}

// ---------------------------------------------------------------------------
// Kernel C: output projection (unchanged from round 6, proven).
// ---------------------------------------------------------------------------
__global__ __launch_bounds__(256) void out_proj_kernel(
    const float* __restrict__ a, const float* __restrict__ W,
    const float* __restrict__ bias, float* __restrict__ dst)
{
    const int n0 = blockIdx.x * 32;
    const int m0 = blockIdx.y * 32;
    const int t  = threadIdx.x;
    const int tx = t & 15;
    const int ty = t >> 4;

    __shared__ float xs[2][32][36];
    __shared__ float wsh[2][32][36];

    float acc[2][2] = {};

    const int arow = t & 31;
    const int akc  = (t >> 5) * 4;
    const int wr   = t >> 3;
    const int wc   = (t & 7) * 4;

    float4 xa = *(const float4*)&a[(m0 + arow) * DM + akc];
    float4 wa = *(const float4*)&W[wr * DM + n0 + wc];
    xs[0][akc + 0][arow] = xa.x; xs[0][akc + 1][arow] = xa.y;
    xs[0][akc + 2][arow] = xa.z; xs[0][akc + 3][arow] = xa.w;
    *(float4*)&wsh[0][wr][wc] = wa;
    __syncthreads();

    int cur = 0;
    for (int k0 = 32; k0 < DM; k0 += 32) {
        xa = *(const float4*)&a[(m0 + arow) * DM + k0 + akc];
        wa = *(const float4*)&W[(k0 + wr) * DM + n0 + wc];
        #pragma unroll
        for (int kk = 0; kk < 32; kk++) {
            float2 a2 = *(const float2*)&xs[cur][kk][ty * 2];
            float2 b2 = *(const float2*)&wsh[cur][kk][tx * 2];
            acc[0][0] += a2.x * b2.x; acc[0][1] += a2.x * b2.y;
            acc[1][0] += a2.y * b2.x; acc[1][1] += a2.y * b2.y;
        }
        const int nxt = cur ^ 1;
        xs[nxt][akc + 0][arow] = xa.x; xs[nxt][akc + 1][arow] = xa.y;
        xs[nxt][akc + 2][arow] = xa.z; xs[nxt][akc + 3][arow] = xa.w;
        *(float4*)&wsh[nxt][wr][wc] = wa;
        __syncthreads();
        cur = nxt;
    }
    #pragma unroll
    for (int kk = 0; kk < 32; kk++) {
        float2 a2 = *(const float2*)&xs[cur][kk][ty * 2];
        float2 b2 = *(const float2*)&wsh[cur][kk][tx * 2];
        acc[0][0] += a2.x * b2.x; acc[0][1] += a2.x * b2.y;
        acc[1][0] += a2.y * b2.x; acc[1][1] += a2.y * b2.y;
    }

    #pragma unroll
    for (int j = 0; j < 2; j++) {
        const int cidx = n0 + tx * 2 + j;
        const float bb = bias[cidx];
        #pragma unroll
        for (int i = 0; i < 2; i++) {
            const int row = m0 + ty * 2 + i;
            dst[row * DM + cidx] = acc[i][j] + bb;
        }
    }
}

// ---------------------------------------------------------------------------
extern "C" void kernel_launch(void* const* d_in, const int* in_sizes, int n_in,
                              void* d_out, int out_size, void* d_ws, size_t ws_size,
                              hipStream_t stream)
{
    const float* x  = (const float*)d_in[0];
    const float* Wq = (const float*)d_in[1];
    const float* bq = (const float*)d_in[2];
    const float* Wk = (const float*)d_in[3];
    const float* bk = (const float*)d_in[4];
    const float* Wv = (const float*)d_in[5];
    const float* bv = (const float*)d_in[6];
    const float* Wo = (const float*)d_in[7];
    const float* bo = (const float*)d_in[8];
    float* out = (float*)d_out;

    float* ws      = (float*)d_ws;
    float* q       = ws;                      // [8][1024][32] = 262144
    float* k       = q + 262144;
    float* v       = k + 262144;
    float* attn    = v + 262144;              // [1024][256]  = 262144
    float* part_o  = attn + 262144;           // 8*16*NS*2048 = 1048576
    float* part_l  = part_o + 1048576;        // 8*16*NS*64   = 32768
    // total ~8.5 MB

    qkv_proj_kernel<<<dim3(4, 32, 3), 256, 0, stream>>>(x, Wq, bq, Wk, bk, Wv, bv, q, k, v);
    attn_kernel<<<dim3(512), 256, 0, stream>>>(q, k, v, part_o, part_l);
    combine_kernel<<<dim3(128), 256, 0, stream>>>(part_o, part_l, attn);
    out_proj_kernel<<<dim3(8, 32), 256, 0, stream>>>(attn, Wo, bo, out);
}

// Round 9
// 109.176 us; speedup vs baseline: 1.1281x; 1.0238x over previous
//
#include <hip/hip_runtime.h>
#include <hip/hip_bf16.h>
#include <math.h>

#define S_LEN 1024
#define DM    256
#define DU    32
#define TEMPF 5.0f
#define NS    4          // attention j-splits

typedef float f32x4  __attribute__((ext_vector_type(4)));
typedef short bf16x8 __attribute__((ext_vector_type(8)));   // 8 bf16 (4 VGPRs)

__device__ __forceinline__ unsigned short f32_to_bf16_rne(float x) {
    unsigned int b = __float_as_uint(x);
    b += 0x7FFFu + ((b >> 16) & 1u);
    return (unsigned short)(b >> 16);
}

// split f into bf16 hi + bf16 lo (hi+lo ~= f to ~2^-17 rel)
__device__ __forceinline__ void split_bf16(float f, unsigned short& h, unsigned short& l) {
    h = f32_to_bf16_rne(f);
    float hf = __uint_as_float((unsigned int)h << 16);
    l = f32_to_bf16_rne(f - hf);
}

// ---------------------------------------------------------------------------
// Kernel A: fused QKV projection via split-bf16 MFMA.
// out = act(x @ W + b); sigmoid for Q,K (mat 0,1); writes [h][s][du].
// 64x64 tile, BK=32 (= MFMA K), 4 waves, dbuf LDS, 3-MFMA split product
// (hi*hi + lo*hi + hi*lo -> ~fp32 accuracy).  Grid (12, 16) = 192 blocks.
// A staged [m][k] bf16, B staged [n][k] bf16 (attn-proven fragment layouts).
// ---------------------------------------------------------------------------
__global__ __launch_bounds__(256) void qkv_proj_kernel(
    const float* __restrict__ x,
    const float* __restrict__ Wq, const float* __restrict__ bq,
    const float* __restrict__ Wk, const float* __restrict__ bk,
    const float* __restrict__ Wv, const float* __restrict__ bv,
    float* __restrict__ qo, float* __restrict__ ko, float* __restrict__ vo)
{
    const int n0g = blockIdx.x * 64;       // 0..704 over [Wq|Wk|Wv] cols
    const int mat = n0g >> 8;
    const int n0  = n0g & 255;
    const float* __restrict__ W    = (mat == 0) ? Wq : ((mat == 1) ? Wk : Wv);
    const float* __restrict__ bias = (mat == 0) ? bq : ((mat == 1) ? bk : bv);
    float* __restrict__ dst        = (mat == 0) ? qo : ((mat == 1) ? ko : vo);

    const int m0   = blockIdx.y * 64;
    const int t    = threadIdx.x;
    const int w    = t >> 6;
    const int lane = t & 63;
    const int fm   = lane & 15;
    const int quad = lane >> 4;
    const int q8   = quad * 8;

    __shared__ __align__(16) unsigned short Ah[2][64][40], Al[2][64][40];
    __shared__ __align__(16) unsigned short Bh[2][64][40], Bl[2][64][40];

    // staging maps
    const int xr  = t >> 2;          // A row 0..63
    const int xf  = (t & 3) * 8;     // A k-offset 0,8,16,24
    const int wn  = t & 63;          // B col 0..63 (coalesced per inst)
    const int wkc = (t >> 6) * 8;    // B k-chunk 0,8,16,24

    f32x4 acc[4];
    #pragma unroll
    for (int nt = 0; nt < 4; nt++)
        #pragma unroll
        for (int i = 0; i < 4; i++) acc[nt][i] = 0.0f;

    const float* xbase = x + (m0 + xr) * DM + xf;
    float xa[8], wv[8];

    // load step 0
    {
        float4 a0 = *(const float4*)xbase;
        float4 a1 = *(const float4*)(xbase + 4);
        xa[0]=a0.x; xa[1]=a0.y; xa[2]=a0.z; xa[3]=a0.w;
        xa[4]=a1.x; xa[5]=a1.y; xa[6]=a1.z; xa[7]=a1.w;
        #pragma unroll
        for (int i = 0; i < 8; i++) wv[i] = W[(wkc + i) * DM + n0 + wn];
    }
    // store tile 0
    {
        bf16x8 vh, vl;
        #pragma unroll
        for (int i = 0; i < 8; i++) { unsigned short h,l; split_bf16(xa[i],h,l); vh[i]=(short)h; vl[i]=(short)l; }
        *(bf16x8*)&Ah[0][xr][xf] = vh; *(bf16x8*)&Al[0][xr][xf] = vl;
        #pragma unroll
        for (int i = 0; i < 8; i++) { unsigned short h,l; split_bf16(wv[i],h,l); vh[i]=(short)h; vl[i]=(short)l; }
        *(bf16x8*)&Bh[0][wn][wkc] = vh; *(bf16x8*)&Bl[0][wn][wkc] = vl;
    }
    __syncthreads();

    int buf = 0;
    for (int step = 0; step < 8; step++) {
        if (step < 7) {
            const float* xp = xbase + (step + 1) * 32;
            float4 a0 = *(const float4*)xp;
            float4 a1 = *(const float4*)(xp + 4);
            xa[0]=a0.x; xa[1]=a0.y; xa[2]=a0.z; xa[3]=a0.w;
            xa[4]=a1.x; xa[5]=a1.y; xa[6]=a1.z; xa[7]=a1.w;
            #pragma unroll
            for (int i = 0; i < 8; i++)
                wv[i] = W[((step + 1) * 32 + wkc + i) * DM + n0 + wn];
        }
        // compute current buffer
        {
            bf16x8 ah = *(const bf16x8*)&Ah[buf][16 * w + fm][q8];
            bf16x8 al = *(const bf16x8*)&Al[buf][16 * w + fm][q8];
            #pragma unroll
            for (int nt = 0; nt < 4; nt++) {
                bf16x8 bh = *(const bf16x8*)&Bh[buf][nt * 16 + fm][q8];
                bf16x8 bl = *(const bf16x8*)&Bl[buf][nt * 16 + fm][q8];
                acc[nt] = __builtin_amdgcn_mfma_f32_16x16x32_bf16(ah, bh, acc[nt], 0, 0, 0);
                acc[nt] = __builtin_amdgcn_mfma_f32_16x16x32_bf16(al, bh, acc[nt], 0, 0, 0);
                acc[nt] = __builtin_amdgcn_mfma_f32_16x16x32_bf16(ah, bl, acc[nt], 0, 0, 0);
            }
        }
        if (step < 7) {
            const int nb = buf ^ 1;
            bf16x8 vh, vl;
            #pragma unroll
            for (int i = 0; i < 8; i++) { unsigned short h,l; split_bf16(xa[i],h,l); vh[i]=(short)h; vl[i]=(short)l; }
            *(bf16x8*)&Ah[nb][xr][xf] = vh; *(bf16x8*)&Al[nb][xr][xf] = vl;
            #pragma unroll
            for (int i = 0; i < 8; i++) { unsigned short h,l; split_bf16(wv[i],h,l); vh[i]=(short)h; vl[i]=(short)l; }
            *(bf16x8*)&Bh[nb][wn][wkc] = vh; *(bf16x8*)&Bl[nb][wn][wkc] = vl;
            __syncthreads();
            buf = nb;
        }
    }

    // epilogue: bias (+sigmoid), store to [h][s][du]
    #pragma unroll
    for (int nt = 0; nt < 4; nt++) {
        const int col = n0 + nt * 16 + fm;
        const float bb = bias[col];
        const int hh = col >> 5;
        const int dd = col & 31;
        float* dp = dst + hh * (S_LEN * DU) + dd;
        #pragma unroll
        for (int reg = 0; reg < 4; reg++) {
            const int row = m0 + 16 * w + quad * 4 + reg;
            float val = acc[nt][reg] + bb;
            if (mat < 2) val = 1.0f / (1.0f + __expf(-val));
            dp[row * DU] = val;
        }
    }
}

// ---------------------------------------------------------------------------
// Kernel B: fuzzy-implication attention (unchanged from round 8, proven).
// ---------------------------------------------------------------------------
__global__ __launch_bounds__(256, 2) void attn_kernel(
    const float* __restrict__ q, const float* __restrict__ k,
    const float* __restrict__ v,
    float* __restrict__ part_o, float* __restrict__ part_l)
{
    const int bid = blockIdx.x;
    const int it4 = 15 - (bid >> 5);      // LPT: heavy first
    const int sub = bid & 31;
    const int h   = sub & 7;
    const int s   = sub >> 3;             // split 0..NS-1
    const int t   = threadIdx.x;
    const int r   = t >> 4;               // 0..15
    const int c   = t & 15;               // 0..15
    const int w   = t >> 6;               // wave 0..3
    const int i0  = it4 * 64;

    __shared__ __align__(16) float          Ks[64][36];
    __shared__ __align__(16) unsigned short Vt[32][88];   // [d][j] bf16 (B-op)
    __shared__ __align__(16) unsigned short Ps[64][88];   // [row][j] bf16 (A-op)

    float qreg[4][32];
    #pragma unroll
    for (int kq = 0; kq < 4; kq++) {
        const float* qrow = q + h * (S_LEN * DU) + (i0 + r + 16 * kq) * DU;
        #pragma unroll
        for (int d4 = 0; d4 < 8; d4++) {
            float4 qv = *(const float4*)&qrow[d4 * 4];
            qreg[kq][d4*4+0] = qv.x; qreg[kq][d4*4+1] = qv.y;
            qreg[kq][d4*4+2] = qv.z; qreg[kq][d4*4+3] = qv.w;
        }
    }

    float lpart[4] = {0.0f, 0.0f, 0.0f, 0.0f};
    f32x4 acc0 = {0.0f, 0.0f, 0.0f, 0.0f};
    f32x4 acc1 = {0.0f, 0.0f, 0.0f, 0.0f};

    const int jr = t >> 2;
    const int d0 = (t & 3) * 8;
    const float* kbase = k + h * (S_LEN * DU);
    const float* vbase = v + h * (S_LEN * DU);

    const int lane = t & 63;
    const int m    = lane & 15;
    const int quad = lane >> 4;

    const int njt = it4 + 1;
    float4 ka, kb, va, vb;
    if (s < njt) {
        const float* kp = kbase + (s * 64 + jr) * DU + d0;
        const float* vp = vbase + (s * 64 + jr) * DU + d0;
        ka = *(const float4*)kp; kb = *(const float4*)(kp + 4);
        va = *(const float4*)vp; vb = *(const float4*)(vp + 4);
    }

    for (int jt = s; jt < njt; jt += NS) {
        __syncthreads();
        *(float4*)&Ks[jr][d0]     = ka;
        *(float4*)&Ks[jr][d0 + 4] = kb;
        {
            float vv[8] = {va.x, va.y, va.z, va.w, vb.x, vb.y, vb.z, vb.w};
            #pragma unroll
            for (int i = 0; i < 8; i++)
                Vt[d0 + i][jr] = f32_to_bf16_rne(vv[i]);
        }
        __syncthreads();
        if (jt + NS < njt) {
            const float* kp = kbase + ((jt + NS) * 64 + jr) * DU + d0;
            const float* vp = vbase + ((jt + NS) * 64 + jr) * DU + d0;
            ka = *(const float4*)kp; kb = *(const float4*)(kp + 4);
            va = *(const float4*)vp; vb = *(const float4*)(vp + 4);
        }

        #pragma unroll
        for (int q4 = 0; q4 < 4; q4++) {
            const int jj  = c + q4 * 16;
            const int jgl = jt * 64 + jj;
            float sacc[4] = {0.0f, 0.0f, 0.0f, 0.0f};
            #pragma unroll
            for (int d = 0; d < 32; d += 4) {
                float4 k4 = *(const float4*)&Ks[jj][d];
                #pragma unroll
                for (int kq = 0; kq < 4; kq++) {
                    sacc[kq] += fmaxf(qreg[kq][d+0] - k4.x, 0.0f)
                              + fmaxf(qreg[kq][d+1] - k4.y, 0.0f)
                              + fmaxf(qreg[kq][d+2] - k4.z, 0.0f)
                              + fmaxf(qreg[kq][d+3] - k4.w, 0.0f);
                }
            }
            #pragma unroll
            for (int kq = 0; kq < 4; kq++) {
                const int ig = i0 + r + 16 * kq;
                const float p = (jgl <= ig)
                    ? __expf(TEMPF - (TEMPF / 32.0f) * sacc[kq]) : 0.0f;
                lpart[kq] += p;
                Ps[r + 16 * kq][jj] = f32_to_bf16_rne(p);
            }
        }
        __syncthreads();

        #pragma unroll
        for (int kc = 0; kc < 2; kc++) {
            bf16x8 a  = *(const bf16x8*)&Ps[16 * w + m][kc * 32 + quad * 8];
            bf16x8 b0 = *(const bf16x8*)&Vt[m]     [kc * 32 + quad * 8];
            bf16x8 b1 = *(const bf16x8*)&Vt[m + 16][kc * 32 + quad * 8];
            acc0 = __builtin_amdgcn_mfma_f32_16x16x32_bf16(a, b0, acc0, 0, 0, 0);
            acc1 = __builtin_amdgcn_mfma_f32_16x16x32_bf16(a, b1, acc1, 0, 0, 0);
        }
    }

    #pragma unroll
    for (int off = 8; off; off >>= 1)
        #pragma unroll
        for (int kq = 0; kq < 4; kq++)
            lpart[kq] += __shfl_xor(lpart[kq], off, 16);

    const int pbase = (h * 16 + it4) * NS + s;
    float* po = part_o + (size_t)pbase * 2048;
    #pragma unroll
    for (int reg = 0; reg < 4; reg++) {
        const int row = 16 * w + quad * 4 + reg;
        po[row * 32 + m]      = acc0[reg];
        po[row * 32 + m + 16] = acc1[reg];
    }
    if (c == 0) {
        #pragma unroll
        for (int kq = 0; kq < 4; kq++)
            part_l[pbase * 64 + r + 16 * kq] = lpart[kq];
    }
}

// ---------------------------------------------------------------------------
// Kernel C: output projection FUSED with split-combine.
// out = (combine(part_o, part_l)) @ Wo + bo.  BK=32 = one head; m-tile 64
// = one it4 tile, so A-staging sums the NS split partials and normalizes
// by sum(part_l) inline.  Same split-bf16 3-MFMA core.  Grid (4,16)=64 blk.
// ---------------------------------------------------------------------------
__global__ __launch_bounds__(256) void out_proj_kernel(
    const float* __restrict__ part_o, const float* __restrict__ part_l,
    const float* __restrict__ W, const float* __restrict__ bias,
    float* __restrict__ dst)
{
    const int n0  = blockIdx.x * 64;
    const int it4 = blockIdx.y;        // m-tile == attention i-tile
    const int m0  = it4 * 64;
    const int t    = threadIdx.x;
    const int w    = t >> 6;
    const int lane = t & 63;
    const int fm   = lane & 15;
    const int quad = lane >> 4;
    const int q8   = quad * 8;

    __shared__ __align__(16) unsigned short Ah[2][64][40], Al[2][64][40];
    __shared__ __align__(16) unsigned short Bh[2][64][40], Bl[2][64][40];

    const int xr  = t >> 2;          // A row (row within i-tile) 0..63
    const int xf  = (t & 3) * 8;     // d-offset 0,8,16,24
    const int wn  = t & 63;
    const int wkc = (t >> 6) * 8;

    f32x4 acc[4];
    #pragma unroll
    for (int nt = 0; nt < 4; nt++)
        #pragma unroll
        for (int i = 0; i < 4; i++) acc[nt][i] = 0.0f;

    float xa[8], wv[8];

    // A load for head h (= k-step): sum NS splits of part_o, divide by sum l
    auto loadA = [&](int h) {
        const int base = (h * 16 + it4) * NS;
        float o[8] = {0,0,0,0,0,0,0,0};
        float l = 0.0f;
        #pragma unroll
        for (int s2 = 0; s2 < NS; s2++) {
            const float* po = part_o + (size_t)(base + s2) * 2048 + xr * 32 + xf;
            float4 p0 = *(const float4*)po;
            float4 p1 = *(const float4*)(po + 4);
            o[0]+=p0.x; o[1]+=p0.y; o[2]+=p0.z; o[3]+=p0.w;
            o[4]+=p1.x; o[5]+=p1.y; o[6]+=p1.z; o[7]+=p1.w;
            l += part_l[(base + s2) * 64 + xr];
        }
        const float inv = 1.0f / l;
        #pragma unroll
        for (int i = 0; i < 8; i++) xa[i] = o[i] * inv;
    };
    auto loadW = [&](int k0) {
        #pragma unroll
        for (int i = 0; i < 8; i++) wv[i] = W[(k0 + wkc + i) * DM + n0 + wn];
    };
    auto storeT = [&](int b) {
        bf16x8 vh, vl;
        #pragma unroll
        for (int i = 0; i < 8; i++) { unsigned short h,l; split_bf16(xa[i],h,l); vh[i]=(short)h; vl[i]=(short)l; }
        *(bf16x8*)&Ah[b][xr][xf] = vh; *(bf16x8*)&Al[b][xr][xf] = vl;
        #pragma unroll
        for (int i = 0; i < 8; i++) { unsigned short h,l; split_bf16(wv[i],h,l); vh[i]=(short)h; vl[i]=(short)l; }
        *(bf16x8*)&Bh[b][wn][wkc] = vh; *(bf16x8*)&Bl[b][wn][wkc] = vl;
    };

    loadA(0); loadW(0);
    storeT(0);
    __syncthreads();

    int buf = 0;
    for (int step = 0; step < 8; step++) {
        if (step < 7) { loadA(step + 1); loadW((step + 1) * 32); }
        {
            bf16x8 ah = *(const bf16x8*)&Ah[buf][16 * w + fm][q8];
            bf16x8 al = *(const bf16x8*)&Al[buf][16 * w + fm][q8];
            #pragma unroll
            for (int nt = 0; nt < 4; nt++) {
                bf16x8 bh = *(const bf16x8*)&Bh[buf][nt * 16 + fm][q8];
                bf16x8 bl = *(const bf16x8*)&Bl[buf][nt * 16 + fm][q8];
                acc[nt] = __builtin_amdgcn_mfma_f32_16x16x32_bf16(ah, bh, acc[nt], 0, 0, 0);
                acc[nt] = __builtin_amdgcn_mfma_f32_16x16x32_bf16(al, bh, acc[nt], 0, 0, 0);
                acc[nt] = __builtin_amdgcn_mfma_f32_16x16x32_bf16(ah, bl, acc[nt], 0, 0, 0);
            }
        }
        if (step < 7) {
            const int nb = buf ^ 1;
            storeT(nb);
            __syncthreads();
            buf = nb;
        }
    }

    #pragma unroll
    for (int nt = 0; nt < 4; nt++) {
        const int col = n0 + nt * 16 + fm;
        const float bb = bias[col];
        #pragma unroll
        for (int reg = 0; reg < 4; reg++) {
            const int row = m0 + 16 * w + quad * 4 + reg;
            dst[row * DM + col] = acc[nt][reg] + bb;
        }
    }
}

// ---------------------------------------------------------------------------
extern "C" void kernel_launch(void* const* d_in, const int* in_sizes, int n_in,
                              void* d_out, int out_size, void* d_ws, size_t ws_size,
                              hipStream_t stream)
{
    const float* x  = (const float*)d_in[0];
    const float* Wq = (const float*)d_in[1];
    const float* bq = (const float*)d_in[2];
    const float* Wk = (const float*)d_in[3];
    const float* bk = (const float*)d_in[4];
    const float* Wv = (const float*)d_in[5];
    const float* bv = (const float*)d_in[6];
    const float* Wo = (const float*)d_in[7];
    const float* bo = (const float*)d_in[8];
    float* out = (float*)d_out;

    float* ws      = (float*)d_ws;
    float* q       = ws;                      // [8][1024][32] = 262144
    float* k       = q + 262144;
    float* v       = k + 262144;
    float* part_o  = v + 262144;              // 8*16*NS*2048 = 1048576
    float* part_l  = part_o + 1048576;        // 8*16*NS*64   = 32768
    // total ~7.5 MB

    qkv_proj_kernel<<<dim3(12, 16), 256, 0, stream>>>(x, Wq, bq, Wk, bk, Wv, bv, q, k, v);
    attn_kernel<<<dim3(512), 256, 0, stream>>>(q, k, v, part_o, part_l);
    out_proj_kernel<<<dim3(4, 16), 256, 0, stream>>>(part_o, part_l, Wo, bo, out);
}

// Round 10
// 107.132 us; speedup vs baseline: 1.1496x; 1.0191x over previous
//
#include <hip/hip_runtime.h>
#include <hip/hip_bf16.h>
#include <math.h>

#define S_LEN 1024
#define DM    256
#define DU    32
#define TEMPF 5.0f
#define NS    4          // attention j-splits

typedef float    f32x4  __attribute__((ext_vector_type(4)));
typedef short    bf16x8 __attribute__((ext_vector_type(8)));   // 8 bf16 (4 VGPRs)
typedef _Float16 f16x2  __attribute__((ext_vector_type(2)));
typedef _Float16 f16x8  __attribute__((ext_vector_type(8)));

__device__ __forceinline__ unsigned short f32_to_bf16_rne(float x) {
    unsigned int b = __float_as_uint(x);
    b += 0x7FFFu + ((b >> 16) & 1u);
    return (unsigned short)(b >> 16);
}

// split f into bf16 hi + bf16 lo (hi+lo ~= f to ~2^-17 rel)
__device__ __forceinline__ void split_bf16(float f, unsigned short& h, unsigned short& l) {
    h = f32_to_bf16_rne(f);
    float hf = __uint_as_float((unsigned int)h << 16);
    l = f32_to_bf16_rne(f - hf);
}

// ---------------------------------------------------------------------------
// Kernel A: fused QKV projection via split-bf16 MFMA (unchanged from R9).
// ---------------------------------------------------------------------------
__global__ __launch_bounds__(256) void qkv_proj_kernel(
    const float* __restrict__ x,
    const float* __restrict__ Wq, const float* __restrict__ bq,
    const float* __restrict__ Wk, const float* __restrict__ bk,
    const float* __restrict__ Wv, const float* __restrict__ bv,
    float* __restrict__ qo, float* __restrict__ ko, float* __restrict__ vo)
{
    const int n0g = blockIdx.x * 64;       // 0..704 over [Wq|Wk|Wv] cols
    const int mat = n0g >> 8;
    const int n0  = n0g & 255;
    const float* __restrict__ W    = (mat == 0) ? Wq : ((mat == 1) ? Wk : Wv);
    const float* __restrict__ bias = (mat == 0) ? bq : ((mat == 1) ? bk : bv);
    float* __restrict__ dst        = (mat == 0) ? qo : ((mat == 1) ? ko : vo);

    const int m0   = blockIdx.y * 64;
    const int t    = threadIdx.x;
    const int w    = t >> 6;
    const int lane = t & 63;
    const int fm   = lane & 15;
    const int quad = lane >> 4;
    const int q8   = quad * 8;

    __shared__ __align__(16) unsigned short Ah[2][64][40], Al[2][64][40];
    __shared__ __align__(16) unsigned short Bh[2][64][40], Bl[2][64][40];

    const int xr  = t >> 2;
    const int xf  = (t & 3) * 8;
    const int wn  = t & 63;
    const int wkc = (t >> 6) * 8;

    f32x4 acc[4];
    #pragma unroll
    for (int nt = 0; nt < 4; nt++)
        #pragma unroll
        for (int i = 0; i < 4; i++) acc[nt][i] = 0.0f;

    const float* xbase = x + (m0 + xr) * DM + xf;
    float xa[8], wv[8];

    {
        float4 a0 = *(const float4*)xbase;
        float4 a1 = *(const float4*)(xbase + 4);
        xa[0]=a0.x; xa[1]=a0.y; xa[2]=a0.z; xa[3]=a0.w;
        xa[4]=a1.x; xa[5]=a1.y; xa[6]=a1.z; xa[7]=a1.w;
        #pragma unroll
        for (int i = 0; i < 8; i++) wv[i] = W[(wkc + i) * DM + n0 + wn];
    }
    {
        bf16x8 vh, vl;
        #pragma unroll
        for (int i = 0; i < 8; i++) { unsigned short h,l; split_bf16(xa[i],h,l); vh[i]=(short)h; vl[i]=(short)l; }
        *(bf16x8*)&Ah[0][xr][xf] = vh; *(bf16x8*)&Al[0][xr][xf] = vl;
        #pragma unroll
        for (int i = 0; i < 8; i++) { unsigned short h,l; split_bf16(wv[i],h,l); vh[i]=(short)h; vl[i]=(short)l; }
        *(bf16x8*)&Bh[0][wn][wkc] = vh; *(bf16x8*)&Bl[0][wn][wkc] = vl;
    }
    __syncthreads();

    int buf = 0;
    for (int step = 0; step < 8; step++) {
        if (step < 7) {
            const float* xp = xbase + (step + 1) * 32;
            float4 a0 = *(const float4*)xp;
            float4 a1 = *(const float4*)(xp + 4);
            xa[0]=a0.x; xa[1]=a0.y; xa[2]=a0.z; xa[3]=a0.w;
            xa[4]=a1.x; xa[5]=a1.y; xa[6]=a1.z; xa[7]=a1.w;
            #pragma unroll
            for (int i = 0; i < 8; i++)
                wv[i] = W[((step + 1) * 32 + wkc + i) * DM + n0 + wn];
        }
        {
            bf16x8 ah = *(const bf16x8*)&Ah[buf][16 * w + fm][q8];
            bf16x8 al = *(const bf16x8*)&Al[buf][16 * w + fm][q8];
            #pragma unroll
            for (int nt = 0; nt < 4; nt++) {
                bf16x8 bh = *(const bf16x8*)&Bh[buf][nt * 16 + fm][q8];
                bf16x8 bl = *(const bf16x8*)&Bl[buf][nt * 16 + fm][q8];
                acc[nt] = __builtin_amdgcn_mfma_f32_16x16x32_bf16(ah, bh, acc[nt], 0, 0, 0);
                acc[nt] = __builtin_amdgcn_mfma_f32_16x16x32_bf16(al, bh, acc[nt], 0, 0, 0);
                acc[nt] = __builtin_amdgcn_mfma_f32_16x16x32_bf16(ah, bl, acc[nt], 0, 0, 0);
            }
        }
        if (step < 7) {
            const int nb = buf ^ 1;
            bf16x8 vh, vl;
            #pragma unroll
            for (int i = 0; i < 8; i++) { unsigned short h,l; split_bf16(xa[i],h,l); vh[i]=(short)h; vl[i]=(short)l; }
            *(bf16x8*)&Ah[nb][xr][xf] = vh; *(bf16x8*)&Al[nb][xr][xf] = vl;
            #pragma unroll
            for (int i = 0; i < 8; i++) { unsigned short h,l; split_bf16(wv[i],h,l); vh[i]=(short)h; vl[i]=(short)l; }
            *(bf16x8*)&Bh[nb][wn][wkc] = vh; *(bf16x8*)&Bl[nb][wn][wkc] = vl;
            __syncthreads();
            buf = nb;
        }
    }

    #pragma unroll
    for (int nt = 0; nt < 4; nt++) {
        const int col = n0 + nt * 16 + fm;
        const float bb = bias[col];
        const int hh = col >> 5;
        const int dd = col & 31;
        float* dp = dst + hh * (S_LEN * DU) + dd;
        #pragma unroll
        for (int reg = 0; reg < 4; reg++) {
            const int row = m0 + 16 * w + quad * 4 + reg;
            float val = acc[nt][reg] + bb;
            if (mat < 2) val = 1.0f / (1.0f + __expf(-val));
            dp[row * DU] = val;
        }
    }
}

// ---------------------------------------------------------------------------
// Kernel B: fuzzy-implication attention.  R8 structure; phase-1 score now
// f16-packed: K staged as f16 LDS, Q as f16x2 regs; per 2 elems one pk_sub +
// pk_max + v_dot2_f32_f16 (f32 accumulate) — halves score VALU.
// ---------------------------------------------------------------------------
__global__ __launch_bounds__(256, 2) void attn_kernel(
    const float* __restrict__ q, const float* __restrict__ k,
    const float* __restrict__ v,
    float* __restrict__ part_o, float* __restrict__ part_l)
{
    const int bid = blockIdx.x;
    const int it4 = 15 - (bid >> 5);      // LPT: heavy first
    const int sub = bid & 31;
    const int h   = sub & 7;
    const int s   = sub >> 3;             // split 0..NS-1
    const int t   = threadIdx.x;
    const int r   = t >> 4;               // 0..15
    const int c   = t & 15;               // 0..15
    const int w   = t >> 6;               // wave 0..3
    const int i0  = it4 * 64;

    __shared__ __align__(16) _Float16       Kh[64][40];   // [j][d] f16 (score)
    __shared__ __align__(16) unsigned short Vt[32][88];   // [d][j] bf16 (B-op)
    __shared__ __align__(16) unsigned short Ps[64][88];   // [row][j] bf16 (A-op)

    // Q rows as f16x2 pairs (64 VGPRs vs 128 fp32)
    f16x2 qh[4][16];
    #pragma unroll
    for (int kq = 0; kq < 4; kq++) {
        const float* qrow = q + h * (S_LEN * DU) + (i0 + r + 16 * kq) * DU;
        #pragma unroll
        for (int d4 = 0; d4 < 8; d4++) {
            float4 qv = *(const float4*)&qrow[d4 * 4];
            qh[kq][d4*2+0] = (f16x2){(_Float16)qv.x, (_Float16)qv.y};
            qh[kq][d4*2+1] = (f16x2){(_Float16)qv.z, (_Float16)qv.w};
        }
    }
    const f16x2 one2  = {(_Float16)1.0f, (_Float16)1.0f};
    const f16x2 zero2 = {(_Float16)0.0f, (_Float16)0.0f};

    float lpart[4] = {0.0f, 0.0f, 0.0f, 0.0f};
    f32x4 acc0 = {0.0f, 0.0f, 0.0f, 0.0f};
    f32x4 acc1 = {0.0f, 0.0f, 0.0f, 0.0f};

    const int jr = t >> 2;
    const int d0 = (t & 3) * 8;
    const float* kbase = k + h * (S_LEN * DU);
    const float* vbase = v + h * (S_LEN * DU);

    const int lane = t & 63;
    const int m    = lane & 15;
    const int quad = lane >> 4;

    const int njt = it4 + 1;
    float4 ka, kb, va, vb;
    if (s < njt) {
        const float* kp = kbase + (s * 64 + jr) * DU + d0;
        const float* vp = vbase + (s * 64 + jr) * DU + d0;
        ka = *(const float4*)kp; kb = *(const float4*)(kp + 4);
        va = *(const float4*)vp; vb = *(const float4*)(vp + 4);
    }

    for (int jt = s; jt < njt; jt += NS) {
        __syncthreads();
        {
            float kv[8] = {ka.x, ka.y, ka.z, ka.w, kb.x, kb.y, kb.z, kb.w};
            f16x8 kh8;
            #pragma unroll
            for (int i = 0; i < 8; i++) kh8[i] = (_Float16)kv[i];
            *(f16x8*)&Kh[jr][d0] = kh8;
            float vv[8] = {va.x, va.y, va.z, va.w, vb.x, vb.y, vb.z, vb.w};
            #pragma unroll
            for (int i = 0; i < 8; i++)
                Vt[d0 + i][jr] = f32_to_bf16_rne(vv[i]);
        }
        __syncthreads();
        if (jt + NS < njt) {
            const float* kp = kbase + ((jt + NS) * 64 + jr) * DU + d0;
            const float* vp = vbase + ((jt + NS) * 64 + jr) * DU + d0;
            ka = *(const float4*)kp; kb = *(const float4*)(kp + 4);
            va = *(const float4*)vp; vb = *(const float4*)(vp + 4);
        }

        // ---- phase 1: f16-packed scores -> p -> Ps bf16 + l partials ----
        #pragma unroll
        for (int q4 = 0; q4 < 4; q4++) {
            const int jj  = c + q4 * 16;
            const int jgl = jt * 64 + jj;
            float sacc[4] = {0.0f, 0.0f, 0.0f, 0.0f};
            #pragma unroll
            for (int d8 = 0; d8 < 4; d8++) {
                f16x8 k8 = *(const f16x8*)&Kh[jj][d8 * 8];
                #pragma unroll
                for (int p2 = 0; p2 < 4; p2++) {
                    f16x2 kk = {k8[2*p2], k8[2*p2+1]};
                    #pragma unroll
                    for (int kq = 0; kq < 4; kq++) {
                        f16x2 diff = qh[kq][d8*4+p2] - kk;
                        f16x2 mx = __builtin_elementwise_max(diff, zero2);
#if defined(__has_builtin) && __has_builtin(__builtin_amdgcn_fdot2)
                        sacc[kq] = __builtin_amdgcn_fdot2(mx, one2, sacc[kq], false);
#else
                        sacc[kq] += (float)mx[0] + (float)mx[1];
#endif
                    }
                }
            }
            #pragma unroll
            for (int kq = 0; kq < 4; kq++) {
                const int ig = i0 + r + 16 * kq;
                const float p = (jgl <= ig)
                    ? __expf(TEMPF - (TEMPF / 32.0f) * sacc[kq]) : 0.0f;
                lpart[kq] += p;
                Ps[r + 16 * kq][jj] = f32_to_bf16_rne(p);
            }
        }
        __syncthreads();

        // ---- phase 2: PV via MFMA ----
        #pragma unroll
        for (int kc = 0; kc < 2; kc++) {
            bf16x8 a  = *(const bf16x8*)&Ps[16 * w + m][kc * 32 + quad * 8];
            bf16x8 b0 = *(const bf16x8*)&Vt[m]     [kc * 32 + quad * 8];
            bf16x8 b1 = *(const bf16x8*)&Vt[m + 16][kc * 32 + quad * 8];
            acc0 = __builtin_amdgcn_mfma_f32_16x16x32_bf16(a, b0, acc0, 0, 0, 0);
            acc1 = __builtin_amdgcn_mfma_f32_16x16x32_bf16(a, b1, acc1, 0, 0, 0);
        }
    }

    #pragma unroll
    for (int off = 8; off; off >>= 1)
        #pragma unroll
        for (int kq = 0; kq < 4; kq++)
            lpart[kq] += __shfl_xor(lpart[kq], off, 16);

    const int pbase = (h * 16 + it4) * NS + s;
    float* po = part_o + (size_t)pbase * 2048;
    #pragma unroll
    for (int reg = 0; reg < 4; reg++) {
        const int row = 16 * w + quad * 4 + reg;
        po[row * 32 + m]      = acc0[reg];
        po[row * 32 + m + 16] = acc1[reg];
    }
    if (c == 0) {
        #pragma unroll
        for (int kq = 0; kq < 4; kq++)
            part_l[pbase * 64 + r + 16 * kq] = lpart[kq];
    }
}

// ---------------------------------------------------------------------------
// Kernel C: output projection + fused combine.  Widened to 128 blocks
// (32-wide n-tiles) for 2x CU coverage.  Same split-bf16 3-MFMA core.
// ---------------------------------------------------------------------------
__global__ __launch_bounds__(256) void out_proj_kernel(
    const float* __restrict__ part_o, const float* __restrict__ part_l,
    const float* __restrict__ W, const float* __restrict__ bias,
    float* __restrict__ dst)
{
    const int n0  = blockIdx.x * 32;
    const int it4 = blockIdx.y;
    const int m0  = it4 * 64;
    const int t    = threadIdx.x;
    const int w    = t >> 6;
    const int lane = t & 63;
    const int fm   = lane & 15;
    const int quad = lane >> 4;
    const int q8   = quad * 8;

    __shared__ __align__(16) unsigned short Ah[2][64][40], Al[2][64][40];
    __shared__ __align__(16) unsigned short Bh[2][32][40], Bl[2][32][40];

    const int xr  = t >> 2;          // A row 0..63
    const int xf  = (t & 3) * 8;     // d-offset
    const int wn  = t & 31;          // B col 0..31
    const int wkb = (t >> 5) * 4;    // B k-chunk 0,4,..,28

    f32x4 acc[2];
    #pragma unroll
    for (int nt = 0; nt < 2; nt++)
        #pragma unroll
        for (int i = 0; i < 4; i++) acc[nt][i] = 0.0f;

    float xa[8], wv[4];

    auto loadA = [&](int h) {
        const int base = (h * 16 + it4) * NS;
        float o[8] = {0,0,0,0,0,0,0,0};
        float l = 0.0f;
        #pragma unroll
        for (int s2 = 0; s2 < NS; s2++) {
            const float* po = part_o + (size_t)(base + s2) * 2048 + xr * 32 + xf;
            float4 p0 = *(const float4*)po;
            float4 p1 = *(const float4*)(po + 4);
            o[0]+=p0.x; o[1]+=p0.y; o[2]+=p0.z; o[3]+=p0.w;
            o[4]+=p1.x; o[5]+=p1.y; o[6]+=p1.z; o[7]+=p1.w;
            l += part_l[(base + s2) * 64 + xr];
        }
        const float inv = 1.0f / l;
        #pragma unroll
        for (int i = 0; i < 8; i++) xa[i] = o[i] * inv;
    };
    auto loadW = [&](int k0) {
        #pragma unroll
        for (int i = 0; i < 4; i++) wv[i] = W[(k0 + wkb + i) * DM + n0 + wn];
    };
    auto storeT = [&](int b) {
        bf16x8 vh, vl;
        #pragma unroll
        for (int i = 0; i < 8; i++) { unsigned short h,l; split_bf16(xa[i],h,l); vh[i]=(short)h; vl[i]=(short)l; }
        *(bf16x8*)&Ah[b][xr][xf] = vh; *(bf16x8*)&Al[b][xr][xf] = vl;
        ushort4 bh4, bl4;
        unsigned short hh, ll;
        split_bf16(wv[0], hh, ll); bh4.x = hh; bl4.x = ll;
        split_bf16(wv[1], hh, ll); bh4.y = hh; bl4.y = ll;
        split_bf16(wv[2], hh, ll); bh4.z = hh; bl4.z = ll;
        split_bf16(wv[3], hh, ll); bh4.w = hh; bl4.w = ll;
        *(ushort4*)&Bh[b][wn][wkb] = bh4;
        *(ushort4*)&Bl[b][wn][wkb] = bl4;
    };

    loadA(0); loadW(0);
    storeT(0);
    __syncthreads();

    int buf = 0;
    for (int step = 0; step < 8; step++) {
        if (step < 7) { loadA(step + 1); loadW((step + 1) * 32); }
        {
            bf16x8 ah = *(const bf16x8*)&Ah[buf][16 * w + fm][q8];
            bf16x8 al = *(const bf16x8*)&Al[buf][16 * w + fm][q8];
            #pragma unroll
            for (int nt = 0; nt < 2; nt++) {
                bf16x8 bh = *(const bf16x8*)&Bh[buf][nt * 16 + fm][q8];
                bf16x8 bl = *(const bf16x8*)&Bl[buf][nt * 16 + fm][q8];
                acc[nt] = __builtin_amdgcn_mfma_f32_16x16x32_bf16(ah, bh, acc[nt], 0, 0, 0);
                acc[nt] = __builtin_amdgcn_mfma_f32_16x16x32_bf16(al, bh, acc[nt], 0, 0, 0);
                acc[nt] = __builtin_amdgcn_mfma_f32_16x16x32_bf16(ah, bl, acc[nt], 0, 0, 0);
            }
        }
        if (step < 7) {
            const int nb = buf ^ 1;
            storeT(nb);
            __syncthreads();
            buf = nb;
        }
    }

    #pragma unroll
    for (int nt = 0; nt < 2; nt++) {
        const int col = n0 + nt * 16 + fm;
        const float bb = bias[col];
        #pragma unroll
        for (int reg = 0; reg < 4; reg++) {
            const int row = m0 + 16 * w + quad * 4 + reg;
            dst[row * DM + col] = acc[nt][reg] + bb;
        }
    }
}

// ---------------------------------------------------------------------------
extern "C" void kernel_launch(void* const* d_in, const int* in_sizes, int n_in,
                              void* d_out, int out_size, void* d_ws, size_t ws_size,
                              hipStream_t stream)
{
    const float* x  = (const float*)d_in[0];
    const float* Wq = (const float*)d_in[1];
    const float* bq = (const float*)d_in[2];
    const float* Wk = (const float*)d_in[3];
    const float* bk = (const float*)d_in[4];
    const float* Wv = (const float*)d_in[5];
    const float* bv = (const float*)d_in[6];
    const float* Wo = (const float*)d_in[7];
    const float* bo = (const float*)d_in[8];
    float* out = (float*)d_out;

    float* ws      = (float*)d_ws;
    float* q       = ws;                      // [8][1024][32] = 262144
    float* k       = q + 262144;
    float* v       = k + 262144;
    float* part_o  = v + 262144;              // 8*16*NS*2048 = 1048576
    float* part_l  = part_o + 1048576;        // 8*16*NS*64   = 32768
    // total ~7.5 MB

    qkv_proj_kernel<<<dim3(12, 16), 256, 0, stream>>>(x, Wq, bq, Wk, bk, Wv, bv, q, k, v);
    attn_kernel<<<dim3(512), 256, 0, stream>>>(q, k, v, part_o, part_l);
    out_proj_kernel<<<dim3(8, 16), 256, 0, stream>>>(part_o, part_l, Wo, bo, out);
}